// Round 1
// baseline (206.066 us; speedup 1.0000x reference)
//
#include <hip/hip_runtime.h>
#include <hip/hip_cooperative_groups.h>

namespace cg = cooperative_groups;

// out[n] = bump( max_l min_f max_c |A[n,l,c] - B[c,f]| ),  bump(x)=sigmoid(10x)*sigmoid(-10x)
// bump even + strictly decreasing for x>=0  =>  reduce t first, bump once at the end.
// N=64, L=512, F=2048.  A:(64,512,2) f32, B:(1,2,2048) f32, out:(64,1) f32.
//
// Single cooperative kernel: phase 1 = per-block max-of-min into ws[block],
// grid sync, phase 2 = block 0 finalizes (removes the second dispatch + gap).

#define NN 64
#define LL 512
#define FF 2048
#define P  8   // pairs per wave (lanes stripe f)

__global__ __launch_bounds__(256) void psl_fused_kernel(
    const float* __restrict__ A, const float* __restrict__ B,
    float* __restrict__ ws, float* __restrict__ out) {
  const int wave = __builtin_amdgcn_readfirstlane(threadIdx.x >> 6);
  const int lane = threadIdx.x & 63;
  const int p_base = blockIdx.x * 32 + wave * P;   // first pair of this wave

  // A values for this wave's 8 pairs (wave-uniform addresses -> broadcast loads)
  float ax[P], ay[P];
#pragma unroll
  for (int i = 0; i < P; ++i) {
    const float2 a = ((const float2*)A)[p_base + i];
    ax[i] = a.x; ay[i] = a.y;
  }

  const float4* __restrict__ B0 = (const float4*)B;         // B[0,0,:]
  const float4* __restrict__ B1 = (const float4*)(B + FF);  // B[0,1,:]

  float m[P];
#pragma unroll
  for (int i = 0; i < P; ++i) m[i] = 3.4e38f;

  // lanes stripe f in float4 chunks: 64 lanes * 4 = 256 f per iter, 8 iters
#pragma unroll
  for (int it = 0; it < FF / 256; ++it) {
    const int idx = it * 64 + lane;
    const float4 b0 = B0[idx];
    const float4 b1 = B1[idx];
#pragma unroll
    for (int i = 0; i < P; ++i) {
      // abs folds into v_max_f32 input modifiers; min-chain folds into v_min3_f32
      const float v0 = fmaxf(fabsf(ax[i] - b0.x), fabsf(ay[i] - b1.x));
      const float v1 = fmaxf(fabsf(ax[i] - b0.y), fabsf(ay[i] - b1.y));
      const float v2 = fmaxf(fabsf(ax[i] - b0.z), fabsf(ay[i] - b1.z));
      const float v3 = fmaxf(fabsf(ax[i] - b0.w), fabsf(ay[i] - b1.w));
      m[i] = fminf(m[i], fminf(fminf(fminf(v0, v1), v2), v3));
    }
  }

  // per-pair min over f (cross-lane), then max over this wave's 8 pairs
  float t = 0.0f;
#pragma unroll
  for (int i = 0; i < P; ++i) {
#pragma unroll
    for (int off = 32; off; off >>= 1)
      m[i] = fminf(m[i], __shfl_xor(m[i], off));
    t = fmaxf(t, m[i]);
  }

  __shared__ float sm[4];
  if (lane == 0) sm[wave] = t;
  __syncthreads();
  if (threadIdx.x == 0) {
    const float bt = fmaxf(fmaxf(sm[0], sm[1]), fmaxf(sm[2], sm[3]));
    // device-scope store: per-XCD L2s are not cross-coherent
    __hip_atomic_store(&ws[blockIdx.x], bt, __ATOMIC_RELEASE,
                       __HIP_MEMORY_SCOPE_AGENT);
  }

  cg::this_grid().sync();

  // phase 2: block 0, thread n maxes its 16 block results, bumps, stores.
  if (blockIdx.x == 0 && threadIdx.x < NN) {
    const int n = threadIdx.x;
    float t2 = 0.0f;
#pragma unroll
    for (int j = 0; j < (LL / 32); ++j)       // 16 phase-1 blocks per n
      t2 = fmaxf(t2, __hip_atomic_load(&ws[n * (LL / 32) + j],
                                       __ATOMIC_ACQUIRE,
                                       __HIP_MEMORY_SCOPE_AGENT));
    out[n] = (1.0f / (1.0f + expf(-10.0f * t2))) *
             (1.0f / (1.0f + expf( 10.0f * t2)));
  }
}

extern "C" void kernel_launch(void* const* d_in, const int* in_sizes, int n_in,
                              void* d_out, int out_size, void* d_ws, size_t ws_size,
                              hipStream_t stream) {
  const float* A = (const float*)d_in[0];   // (64,512,2)
  const float* B = (const float*)d_in[1];   // (1,2,2048)
  float* out     = (float*)d_out;           // (64,1)
  float* ws      = (float*)d_ws;            // 1024 block results

  void* args[] = {(void*)&A, (void*)&B, (void*)&ws, (void*)&out};
  dim3 grid((NN * LL) / 32);                // 1024 blocks, 4/CU -> co-resident
  dim3 block(256);
  hipLaunchCooperativeKernel((void*)psl_fused_kernel, grid, block, args, 0,
                             stream);
}

// Round 2
// 87.107 us; speedup vs baseline: 2.3657x; 2.3657x over previous
//
#include <hip/hip_runtime.h>

// out[n] = bump( max_l min_f max_c |A[n,l,c] - B[c,f]| ),  bump(x)=sigmoid(10x)*sigmoid(-10x)
// bump even + strictly decreasing for x>=0  =>  reduce t = max-of-min first, bump once.
// N=64, L=512, F=2048.  A:(64,512,2) f32, B:(1,2,2048) f32, out:(64,1) f32.
//
// Single kernel + 4-byte memset node (counter init). Each block writes its
// max-of-min to ws[block] (release, agent scope), bumps an arrival counter;
// the LAST block to arrive finalizes all 64 outputs. No grid-wide spin
// (round-1 lesson: cg grid sync cost ~140us on 1024 blocks).

#define NN   64
#define LL   512
#define FF   2048
#define P    8      // pairs per wave (lanes stripe f)
#define NBLK ((NN * LL) / 32)   // 1024 blocks, 32 pairs each

__global__ __launch_bounds__(256) void psl_reduce_kernel(
    const float* __restrict__ A, const float* __restrict__ B,
    float* __restrict__ ws, float* __restrict__ out) {
  const int wave = __builtin_amdgcn_readfirstlane(threadIdx.x >> 6);
  const int lane = threadIdx.x & 63;
  const int p_base = blockIdx.x * 32 + wave * P;   // first pair of this wave

  // A values for this wave's 8 pairs (wave-uniform addresses -> broadcast loads)
  float ax[P], ay[P];
#pragma unroll
  for (int i = 0; i < P; ++i) {
    const float2 a = ((const float2*)A)[p_base + i];
    ax[i] = a.x; ay[i] = a.y;
  }

  const float4* __restrict__ B0 = (const float4*)B;         // B[0,0,:]
  const float4* __restrict__ B1 = (const float4*)(B + FF);  // B[0,1,:]

  float m[P];
#pragma unroll
  for (int i = 0; i < P; ++i) m[i] = 3.4e38f;

  // lanes stripe f in float4 chunks: 64 lanes * 4 = 256 f per iter, 8 iters
#pragma unroll
  for (int it = 0; it < FF / 256; ++it) {
    const int idx = it * 64 + lane;
    const float4 b0 = B0[idx];
    const float4 b1 = B1[idx];
#pragma unroll
    for (int i = 0; i < P; ++i) {
      // abs folds into v_max_f32 input modifiers; min-chain folds into v_min3_f32
      const float v0 = fmaxf(fabsf(ax[i] - b0.x), fabsf(ay[i] - b1.x));
      const float v1 = fmaxf(fabsf(ax[i] - b0.y), fabsf(ay[i] - b1.y));
      const float v2 = fmaxf(fabsf(ax[i] - b0.z), fabsf(ay[i] - b1.z));
      const float v3 = fmaxf(fabsf(ax[i] - b0.w), fabsf(ay[i] - b1.w));
      m[i] = fminf(m[i], fminf(fminf(fminf(v0, v1), v2), v3));
    }
  }

  // per-pair min over f (cross-lane), then max over this wave's 8 pairs
  float t = 0.0f;
#pragma unroll
  for (int i = 0; i < P; ++i) {
#pragma unroll
    for (int off = 32; off; off >>= 1)
      m[i] = fminf(m[i], __shfl_xor(m[i], off));
    t = fmaxf(t, m[i]);
  }

  __shared__ float sm[4];
  __shared__ int last;
  if (lane == 0) sm[wave] = t;
  __syncthreads();
  if (threadIdx.x == 0) {
    const float bt = fmaxf(fmaxf(sm[0], sm[1]), fmaxf(sm[2], sm[3]));
    // device-scope release store: per-XCD L2s are not cross-coherent
    __hip_atomic_store(&ws[blockIdx.x], bt, __ATOMIC_RELEASE,
                       __HIP_MEMORY_SCOPE_AGENT);
    const int old = __hip_atomic_fetch_add((int*)(ws + NBLK), 1,
                                           __ATOMIC_ACQ_REL,
                                           __HIP_MEMORY_SCOPE_AGENT);
    last = (old == NBLK - 1);
  }
  __syncthreads();

  // last-arriving block finalizes: thread n maxes its 16 block results, bumps.
  if (last && threadIdx.x < NN) {
    const int n = threadIdx.x;
    float t2 = 0.0f;
#pragma unroll
    for (int j = 0; j < (LL / 32); ++j)       // 16 phase-1 blocks per n
      t2 = fmaxf(t2, __hip_atomic_load(&ws[n * (LL / 32) + j],
                                       __ATOMIC_ACQUIRE,
                                       __HIP_MEMORY_SCOPE_AGENT));
    out[n] = (1.0f / (1.0f + expf(-10.0f * t2))) *
             (1.0f / (1.0f + expf( 10.0f * t2)));
  }
}

extern "C" void kernel_launch(void* const* d_in, const int* in_sizes, int n_in,
                              void* d_out, int out_size, void* d_ws, size_t ws_size,
                              hipStream_t stream) {
  const float* A = (const float*)d_in[0];   // (64,512,2)
  const float* B = (const float*)d_in[1];   // (1,2,2048)
  float* out     = (float*)d_out;           // (64,1)
  float* ws      = (float*)d_ws;            // [0,1024): block results; [1024]: counter

  // zero the arrival counter (runs after the harness's ws re-poison each iter)
  hipMemsetAsync((char*)d_ws + NBLK * sizeof(float), 0, sizeof(int), stream);

  psl_reduce_kernel<<<NBLK, 256, 0, stream>>>(A, B, ws, out);
}

// Round 3
// 62.996 us; speedup vs baseline: 3.2711x; 1.3827x over previous
//
#include <hip/hip_runtime.h>

// out[n] = bump( max_l min_f max_c |A[n,l,c] - B[c,f]| ),  bump(x)=sigmoid(10x)*sigmoid(-10x)
// bump even + strictly decreasing for x>=0  =>  reduce t = max-of-min first, bump once.
// N=64, L=512, F=2048.  A:(64,512,2) f32, B:(1,2,2048) f32, out:(64,1) f32.
//
// Two plain kernel nodes (round-0 structure, proven 63.3us).
// Round-1 lesson: cg grid sync = +140us (system-scope spin across 1024 blocks).
// Round-2 lesson: last-block-done arrival counter = +24us (1024 serialized
// agent-scope RMWs on one cacheline + release fences + extra memset node).
// The dumb second kernel is the cheapest cross-block combine on this chip.

#define NN 64
#define LL 512
#define FF 2048
#define P  8   // pairs per wave (lanes stripe f)

// kernel 1: 1024 blocks x 256 threads; block b owns pairs [32b, 32b+32);
// 16 blocks per n. Writes block max-of-min to ws[b] unconditionally (no init needed).
__global__ __launch_bounds__(256) void psl_reduce_kernel(
    const float* __restrict__ A, const float* __restrict__ B,
    float* __restrict__ ws) {
  const int wave = __builtin_amdgcn_readfirstlane(threadIdx.x >> 6);
  const int lane = threadIdx.x & 63;
  const int p_base = blockIdx.x * 32 + wave * P;   // first pair of this wave

  // A values for this wave's 8 pairs (wave-uniform -> scalar loads)
  float ax[P], ay[P];
#pragma unroll
  for (int i = 0; i < P; ++i) {
    const float2 a = ((const float2*)A)[p_base + i];
    ax[i] = a.x; ay[i] = a.y;
  }

  const float4* __restrict__ B0 = (const float4*)B;         // B[0,0,:]
  const float4* __restrict__ B1 = (const float4*)(B + FF);  // B[0,1,:]

  float m[P];
#pragma unroll
  for (int i = 0; i < P; ++i) m[i] = 3.4e38f;

  // lanes stripe f in float4 chunks: 64 lanes * 4 = 256 f per iter, 8 iters
#pragma unroll
  for (int it = 0; it < FF / 256; ++it) {
    const int idx = it * 64 + lane;
    const float4 b0 = B0[idx];
    const float4 b1 = B1[idx];
#pragma unroll
    for (int i = 0; i < P; ++i) {
      // abs folds into v_max_f32 input modifiers; min-chain folds into v_min3_f32
      const float v0 = fmaxf(fabsf(ax[i] - b0.x), fabsf(ay[i] - b1.x));
      const float v1 = fmaxf(fabsf(ax[i] - b0.y), fabsf(ay[i] - b1.y));
      const float v2 = fmaxf(fabsf(ax[i] - b0.z), fabsf(ay[i] - b1.z));
      const float v3 = fmaxf(fabsf(ax[i] - b0.w), fabsf(ay[i] - b1.w));
      m[i] = fminf(m[i], fminf(fminf(fminf(v0, v1), v2), v3));
    }
  }

  // per-pair min over f (cross-lane), then max over this wave's 8 pairs
  float t = 0.0f;
#pragma unroll
  for (int i = 0; i < P; ++i) {
#pragma unroll
    for (int off = 32; off; off >>= 1)
      m[i] = fminf(m[i], __shfl_xor(m[i], off));
    t = fmaxf(t, m[i]);
  }

  __shared__ float sm[4];
  if (lane == 0) sm[wave] = t;
  __syncthreads();
  if (threadIdx.x == 0)
    ws[blockIdx.x] = fmaxf(fmaxf(sm[0], sm[1]), fmaxf(sm[2], sm[3]));
}

// kernel 2: 1 block x 64 threads; thread n maxes its 16 block results
// (4x float4 vector loads, contiguous 64B per n), bumps, stores.
__global__ __launch_bounds__(64) void psl_finalize_kernel(
    const float* __restrict__ ws, float* __restrict__ out) {
  const int n = threadIdx.x;
  const float4* __restrict__ w4 = (const float4*)(ws + n * (LL / 32));
  float t = 0.0f;
#pragma unroll
  for (int j = 0; j < (LL / 32) / 4; ++j) {   // 16 partials = 4 float4s
    const float4 v = w4[j];
    t = fmaxf(t, fmaxf(fmaxf(v.x, v.y), fmaxf(v.z, v.w)));
  }
  out[n] = (1.0f / (1.0f + expf(-10.0f * t))) *
           (1.0f / (1.0f + expf( 10.0f * t)));
}

extern "C" void kernel_launch(void* const* d_in, const int* in_sizes, int n_in,
                              void* d_out, int out_size, void* d_ws, size_t ws_size,
                              hipStream_t stream) {
  const float* A = (const float*)d_in[0];   // (64,512,2)
  const float* B = (const float*)d_in[1];   // (1,2,2048)
  float* out     = (float*)d_out;           // (64,1)
  float* ws      = (float*)d_ws;            // 1024 block results

  const int blocks = (NN * LL) / 32;        // 1024
  psl_reduce_kernel<<<blocks, 256, 0, stream>>>(A, B, ws);
  psl_finalize_kernel<<<1, 64, 0, stream>>>(ws, out);
}